// Round 2
// baseline (1970.790 us; speedup 1.0000x reference)
//
#include <hip/hip_runtime.h>
#include <math.h>

#define NUM_ENTS   100000
#define HD         128
#define NUM_EDGES  2000000
#define RRELU_SLOPE 0.22916666666666666f
#define TM 32
#define LDS_STRIDE 132   // padded f32 row stride

// ---------- bf16 helpers (weights staged in LDS as bf16 to halve LDS) ----------
__device__ __forceinline__ float bf2f(unsigned short h) {
    union { unsigned int u; float f; } v;
    v.u = ((unsigned int)h) << 16;
    return v.f;
}
__device__ __forceinline__ unsigned short f2bf(float f) {
    union { float f; unsigned int u; } v; v.f = f;
    unsigned int r = 0x7fffu + ((v.u >> 16) & 1u);  // round-to-nearest-even
    return (unsigned short)((v.u + r) >> 16);
}

// ---------- 1. per-row inverse L2 norm of ent_emb (f32) ----------
__global__ void __launch_bounds__(256)
norm_kernel(const float* __restrict__ ent, float* __restrict__ invn) {
    const int wid  = threadIdx.x >> 6;
    const int lane = threadIdx.x & 63;
    const int row  = blockIdx.x * 4 + wid;
    if (row >= NUM_ENTS) return;
    const float2 v = *(const float2*)(ent + (size_t)row * HD + lane * 2);
    float ss = v.x * v.x + v.y * v.y;
    #pragma unroll
    for (int m = 1; m < 64; m <<= 1) ss += __shfl_xor(ss, m, 64);
    if (lane == 0) invn[row] = 1.0f / fmaxf(sqrtf(ss), 1e-12f);
}

// ---------- 2. edge scatter: S[dst-base] += norm*(h[src] + rel[etype]) ----------
__global__ void __launch_bounds__(256)
scatter_kernel(const float* __restrict__ ent,
               const float* __restrict__ rel,
               const float* __restrict__ invn,
               const float* __restrict__ enorm,
               const int* __restrict__ src,
               const int* __restrict__ dst,
               const int* __restrict__ ety,
               float* __restrict__ S, int base, int limit) {
    const int e = blockIdx.x * 4 + (threadIdx.x >> 6);
    if (e >= NUM_EDGES) return;
    const int d = dst[e];
    if (d < base || d >= limit) return;            // wave-uniform predicate
    const int lane = threadIdx.x & 63;
    const int s = src[e], t = ety[e];
    const float w   = enorm[e];
    const float inv = invn[s];
    const float2 ev = *(const float2*)(ent + (size_t)s * HD + lane * 2);
    const float2 rv = *(const float2*)(rel + (size_t)t * HD + lane * 2);
    float* p = S + (size_t)(d - base) * HD + lane * 2;
    atomicAdd(p + 0, (ev.x * inv + rv.x) * w);
    atomicAdd(p + 1, (ev.y * inv + rv.y) * w);
}

// ---------- 3. fused: hcur = S@Wn + h@Ws -> rrelu -> gate -> blend ----------
__device__ __forceinline__ void stage_w(const float* __restrict__ W,
                                        unsigned short* sW, int tid) {
    #pragma unroll
    for (int i = 0; i < 16; ++i) {
        const int idx = tid + i * 256;             // 0..4095 float4 chunks
        const float4 v = ((const float4*)W)[idx];
        ushort4 o;
        o.x = f2bf(v.x); o.y = f2bf(v.y); o.z = f2bf(v.z); o.w = f2bf(v.w);
        *(ushort4*)(sW + idx * 4) = o;
    }
}

__device__ __forceinline__ void mm_tile(const unsigned short* sW, const float* sIn,
                                        int r0, int j0, float acc[4][4]) {
    #pragma unroll 4
    for (int k = 0; k < HD; ++k) {
        const ushort4 wv = *(const ushort4*)(sW + k * HD + j0);
        const float w0 = bf2f(wv.x), w1 = bf2f(wv.y), w2 = bf2f(wv.z), w3 = bf2f(wv.w);
        #pragma unroll
        for (int rr = 0; rr < 4; ++rr) {
            const float a = sIn[(r0 + rr) * LDS_STRIDE + k];
            acc[rr][0] += a * w0;
            acc[rr][1] += a * w1;
            acc[rr][2] += a * w2;
            acc[rr][3] += a * w3;
        }
    }
}

__global__ void __launch_bounds__(256)
fused_kernel(const float* __restrict__ S,
             const float* __restrict__ ent,
             const float* __restrict__ invn,
             const float* __restrict__ Wn,
             const float* __restrict__ Ws,
             const float* __restrict__ Wt,
             const float* __restrict__ bias,
             const float* __restrict__ his,
             float* __restrict__ out, int base) {
    __shared__ unsigned short sW[HD * HD];       // 32 KB bf16 weight
    __shared__ float sIn[TM * LDS_STRIDE];       // ~16.9 KB f32 input tile

    const int tid = threadIdx.x;
    const int tx = tid & 31, ty = tid >> 5;
    const int j0 = tx * 4, r0 = ty * 4;
    const int row0 = base + blockIdx.x * TM;     // global first row of tile

    // ---- phase 1: acc = S_tile @ Wn ----
    stage_w(Wn, sW, tid);
    #pragma unroll
    for (int i = tid; i < TM * (HD / 4); i += 256) {
        const int r = i >> 5, c4 = i & 31;
        *(float4*)(sIn + r * LDS_STRIDE + c4 * 4) =
            ((const float4*)(S + (size_t)(blockIdx.x * TM + r) * HD))[c4];
    }
    __syncthreads();
    float acc[4][4] = {{0.f}};
    mm_tile(sW, sIn, r0, j0, acc);
    __syncthreads();

    // ---- phase 2: acc += h_tile @ Ws ; rrelu ----
    stage_w(Ws, sW, tid);
    #pragma unroll
    for (int i = tid; i < TM * (HD / 4); i += 256) {
        const int r = i >> 5, c4 = i & 31;
        const float4 u = *(const float4*)(ent + (size_t)(row0 + r) * HD + c4 * 4);
        const float inv = invn[row0 + r];
        float* p = sIn + r * LDS_STRIDE + c4 * 4;
        p[0] = u.x * inv; p[1] = u.y * inv; p[2] = u.z * inv; p[3] = u.w * inv;
    }
    __syncthreads();
    mm_tile(sW, sIn, r0, j0, acc);

    float hc[4][4];
    #pragma unroll
    for (int rr = 0; rr < 4; ++rr)
        #pragma unroll
        for (int cc = 0; cc < 4; ++cc)
            hc[rr][cc] = acc[rr][cc] >= 0.f ? acc[rr][cc] : RRELU_SLOPE * acc[rr][cc];
    __syncthreads();

    // ---- phase 3: gate = sigmoid(hcur @ Wt + b); out = g*hcur + (1-g)*his ----
    stage_w(Wt, sW, tid);
    #pragma unroll
    for (int rr = 0; rr < 4; ++rr)
        *(float4*)(sIn + (r0 + rr) * LDS_STRIDE + j0) =
            make_float4(hc[rr][0], hc[rr][1], hc[rr][2], hc[rr][3]);
    __syncthreads();

    const float b0 = bias[j0 + 0], b1 = bias[j0 + 1],
                b2 = bias[j0 + 2], b3 = bias[j0 + 3];
    float acc2[4][4];
    #pragma unroll
    for (int rr = 0; rr < 4; ++rr) {
        acc2[rr][0] = b0; acc2[rr][1] = b1; acc2[rr][2] = b2; acc2[rr][3] = b3;
    }
    mm_tile(sW, sIn, r0, j0, acc2);

    #pragma unroll
    for (int rr = 0; rr < 4; ++rr) {
        const int row = row0 + r0 + rr;
        const float4 hv = *(const float4*)(his + (size_t)row * HD + j0);
        const float g0 = 1.f / (1.f + __expf(-acc2[rr][0]));
        const float g1 = 1.f / (1.f + __expf(-acc2[rr][1]));
        const float g2 = 1.f / (1.f + __expf(-acc2[rr][2]));
        const float g3 = 1.f / (1.f + __expf(-acc2[rr][3]));
        float4 o;
        o.x = g0 * hc[rr][0] + (1.f - g0) * hv.x;
        o.y = g1 * hc[rr][1] + (1.f - g1) * hv.y;
        o.z = g2 * hc[rr][2] + (1.f - g2) * hv.z;
        o.w = g3 * hc[rr][3] + (1.f - g3) * hv.w;
        *(float4*)(out + (size_t)row * HD + j0) = o;
    }
}

// ---------- launch ----------
extern "C" void kernel_launch(void* const* d_in, const int* in_sizes, int n_in,
                              void* d_out, int out_size, void* d_ws, size_t ws_size,
                              hipStream_t stream) {
    const float* ent   = (const float*)d_in[0];
    const float* rel   = (const float*)d_in[1];
    const float* his   = (const float*)d_in[2];
    const float* Wn    = (const float*)d_in[3];
    const float* Ws    = (const float*)d_in[4];
    const float* Wt    = (const float*)d_in[5];
    const float* bias  = (const float*)d_in[6];
    const float* enorm = (const float*)d_in[7];
    const int* src = (const int*)d_in[8];
    const int* dst = (const int*)d_in[9];
    const int* ety = (const int*)d_in[10];
    float* out = (float*)d_out;

    // workspace: invn [NUM_ENTS] f32 first, then S chunk sized to fit ws_size.
    float* invn = (float*)d_ws;
    const size_t invn_bytes = ((size_t)NUM_ENTS * sizeof(float) + 511) & ~(size_t)511;
    float* S = (float*)((char*)d_ws + invn_bytes);
    const size_t avail = ws_size > invn_bytes ? ws_size - invn_bytes : 0;
    long cap = (long)(avail / (HD * sizeof(float)));   // rows of S that fit
    cap = (cap / TM) * TM;                             // multiple of tile
    if (cap > NUM_ENTS) cap = NUM_ENTS;
    if (cap < TM) cap = TM;                            // ws assumed >= ~417 KB

    norm_kernel<<<(NUM_ENTS + 3) / 4, 256, 0, stream>>>(ent, invn);

    for (long b = 0; b < NUM_ENTS; b += cap) {
        const long rows = (NUM_ENTS - b < cap) ? (NUM_ENTS - b) : cap;  // mult of 32
        hipMemsetAsync(S, 0, (size_t)rows * HD * sizeof(float), stream);
        scatter_kernel<<<(NUM_EDGES + 3) / 4, 256, 0, stream>>>(
            ent, rel, invn, enorm, src, dst, ety, S, (int)b, (int)(b + rows));
        fused_kernel<<<rows / TM, 256, 0, stream>>>(
            S, ent, invn, Wn, Ws, Wt, bias, his, out, (int)b);
    }
}

// Round 3
// 862.382 us; speedup vs baseline: 2.2853x; 2.2853x over previous
//
#include <hip/hip_runtime.h>
#include <math.h>

#define NUM_ENTS   100000
#define HD         128
#define NUM_EDGES  2000000
#define RRELU_SLOPE 0.22916666666666666f
#define TM 32
#define LDS_STRIDE 132
#define NBLK 391                 // ceil(100000/256)
#define NPAD (NBLK * 256)        // 100096 padded counter range

// ---------- bf16 helpers (weights staged in LDS as bf16) ----------
__device__ __forceinline__ float bf2f(unsigned short h) {
    union { unsigned int u; float f; } v;
    v.u = ((unsigned int)h) << 16;
    return v.f;
}
__device__ __forceinline__ unsigned short f2bf(float f) {
    union { float f; unsigned int u; } v; v.f = f;
    unsigned int r = 0x7fffu + ((v.u >> 16) & 1u);
    return (unsigned short)((v.u + r) >> 16);
}

// ---------- 1. per-row inverse L2 norm ----------
__global__ void __launch_bounds__(256)
norm_kernel(const float* __restrict__ ent, float* __restrict__ invn) {
    const int wid  = threadIdx.x >> 6;
    const int lane = threadIdx.x & 63;
    const int row  = blockIdx.x * 4 + wid;
    if (row >= NUM_ENTS) return;
    const float2 v = *(const float2*)(ent + (size_t)row * HD + lane * 2);
    float ss = v.x * v.x + v.y * v.y;
    #pragma unroll
    for (int m = 1; m < 64; m <<= 1) ss += __shfl_xor(ss, m, 64);
    if (lane == 0) invn[row] = 1.0f / fmaxf(sqrtf(ss), 1e-12f);
}

// ---------- 2a. histogram of dst ----------
__global__ void __launch_bounds__(256)
hist_kernel(const int* __restrict__ dst, int* __restrict__ cnt) {
    for (int e = blockIdx.x * 256 + threadIdx.x; e < NUM_EDGES; e += gridDim.x * 256)
        atomicAdd(&cnt[dst[e]], 1);
}

// ---------- 2b. scan step 1: per-block exclusive scan + block sums ----------
__global__ void __launch_bounds__(256)
scan1_kernel(const int* __restrict__ cnt, int* __restrict__ offs, int* __restrict__ bsum) {
    __shared__ int tmp[256];
    const int t = threadIdx.x;
    const int i = blockIdx.x * 256 + t;
    const int v = cnt[i];
    tmp[t] = v;
    __syncthreads();
    #pragma unroll
    for (int d = 1; d < 256; d <<= 1) {
        const int a = (t >= d) ? tmp[t - d] : 0;
        __syncthreads();
        tmp[t] += a;
        __syncthreads();
    }
    offs[i] = tmp[t] - v;                      // exclusive within block
    if (t == 255) bsum[blockIdx.x] = tmp[255];
}

// ---------- 2c. scan step 2: single-block exclusive scan of block sums ----------
__global__ void __launch_bounds__(512)
scan2_kernel(int* __restrict__ bsum) {
    __shared__ int tmp[512];
    const int t = threadIdx.x;
    const int v = (t < NBLK) ? bsum[t] : 0;
    tmp[t] = v;
    __syncthreads();
    #pragma unroll
    for (int d = 1; d < 512; d <<= 1) {
        const int a = (t >= d) ? tmp[t - d] : 0;
        __syncthreads();
        tmp[t] += a;
        __syncthreads();
    }
    if (t < NBLK) bsum[t] = tmp[t] - v;        // exclusive
}

// ---------- 2d. scan step 3: add block offset; init cursor copy ----------
__global__ void __launch_bounds__(256)
scan3_kernel(int* __restrict__ offs, const int* __restrict__ bsum, int* __restrict__ cur) {
    const int i = blockIdx.x * 256 + threadIdx.x;
    const int o = offs[i] + bsum[blockIdx.x];
    offs[i] = o;
    cur[i]  = o;
}

// ---------- 2e. permutation: perm[pos] = edge id, CSR order by dst ----------
__global__ void __launch_bounds__(256)
permute_kernel(const int* __restrict__ dst, int* __restrict__ cur, int* __restrict__ perm) {
    for (int e = blockIdx.x * 256 + threadIdx.x; e < NUM_EDGES; e += gridDim.x * 256) {
        const int pos = atomicAdd(&cur[dst[e]], 1);
        perm[pos] = e;
    }
}

// ---------- 3. gather: S[d] = sum over in-edges, plain store (no atomics) ----------
__global__ void __launch_bounds__(256)
gather_kernel(const float* __restrict__ ent,
              const float* __restrict__ rel,
              const float* __restrict__ invn,
              const float* __restrict__ enorm,
              const int* __restrict__ src,
              const int* __restrict__ ety,
              const int* __restrict__ offs,
              const int* __restrict__ perm,
              float* __restrict__ S) {
    const int d = blockIdx.x * 4 + (threadIdx.x >> 6);
    if (d >= NUM_ENTS) return;
    const int lane = threadIdx.x & 63;
    const int beg = offs[d], end = offs[d + 1];
    float a0 = 0.f, a1 = 0.f;
    int i = beg;
    int e0 = (i < end) ? perm[i] : 0;          // prefetch first edge id
    while (i < end) {
        const int e = e0;
        if (i + 1 < end) e0 = perm[i + 1];     // prefetch next edge id
        const int s = src[e], t = ety[e];
        const float w   = enorm[e];
        const float inv = invn[s];
        const float2 ev = *(const float2*)(ent + (size_t)s * HD + lane * 2);
        const float2 rv = *(const float2*)(rel + (size_t)t * HD + lane * 2);
        a0 += (ev.x * inv + rv.x) * w;
        a1 += (ev.y * inv + rv.y) * w;
        ++i;
    }
    *(float2*)(S + (size_t)d * HD + lane * 2) = make_float2(a0, a1);
}

// ---------- 4. fused: hcur = S@Wn + h@Ws -> rrelu -> gate -> blend ----------
__device__ __forceinline__ void stage_w(const float* __restrict__ W,
                                        unsigned short* sW, int tid) {
    #pragma unroll
    for (int i = 0; i < 16; ++i) {
        const int idx = tid + i * 256;
        const float4 v = ((const float4*)W)[idx];
        ushort4 o;
        o.x = f2bf(v.x); o.y = f2bf(v.y); o.z = f2bf(v.z); o.w = f2bf(v.w);
        *(ushort4*)(sW + idx * 4) = o;
    }
}

__device__ __forceinline__ void mm_tile(const unsigned short* sW, const float* sIn,
                                        int r0, int j0, float acc[4][4]) {
    #pragma unroll 4
    for (int k = 0; k < HD; ++k) {
        const ushort4 wv = *(const ushort4*)(sW + k * HD + j0);
        const float w0 = bf2f(wv.x), w1 = bf2f(wv.y), w2 = bf2f(wv.z), w3 = bf2f(wv.w);
        #pragma unroll
        for (int rr = 0; rr < 4; ++rr) {
            const float a = sIn[(r0 + rr) * LDS_STRIDE + k];
            acc[rr][0] += a * w0;
            acc[rr][1] += a * w1;
            acc[rr][2] += a * w2;
            acc[rr][3] += a * w3;
        }
    }
}

__global__ void __launch_bounds__(256)
fused_kernel(float* io,                       // aliased: S source rows + out dest rows
             const float* __restrict__ ent,
             const float* __restrict__ invn,
             const float* __restrict__ Wn,
             const float* __restrict__ Ws,
             const float* __restrict__ Wt,
             const float* __restrict__ bias,
             const float* __restrict__ his) {
    __shared__ unsigned short sW[HD * HD];    // 32 KB bf16 weight
    __shared__ float sIn[TM * LDS_STRIDE];    // ~16.9 KB f32 tile

    const int tid = threadIdx.x;
    const int tx = tid & 31, ty = tid >> 5;
    const int j0 = tx * 4, r0 = ty * 4;
    const int row0 = blockIdx.x * TM;

    // ---- phase 1: acc = S_tile @ Wn (S read from io before overwrite) ----
    stage_w(Wn, sW, tid);
    #pragma unroll
    for (int i = tid; i < TM * (HD / 4); i += 256) {
        const int r = i >> 5, c4 = i & 31;
        *(float4*)(sIn + r * LDS_STRIDE + c4 * 4) =
            ((const float4*)(io + (size_t)(row0 + r) * HD))[c4];
    }
    __syncthreads();
    float acc[4][4] = {{0.f}};
    mm_tile(sW, sIn, r0, j0, acc);
    __syncthreads();

    // ---- phase 2: acc += h_tile @ Ws ; rrelu ----
    stage_w(Ws, sW, tid);
    #pragma unroll
    for (int i = tid; i < TM * (HD / 4); i += 256) {
        const int r = i >> 5, c4 = i & 31;
        const float4 u = *(const float4*)(ent + (size_t)(row0 + r) * HD + c4 * 4);
        const float inv = invn[row0 + r];
        float* p = sIn + r * LDS_STRIDE + c4 * 4;
        p[0] = u.x * inv; p[1] = u.y * inv; p[2] = u.z * inv; p[3] = u.w * inv;
    }
    __syncthreads();
    mm_tile(sW, sIn, r0, j0, acc);

    float hc[4][4];
    #pragma unroll
    for (int rr = 0; rr < 4; ++rr)
        #pragma unroll
        for (int cc = 0; cc < 4; ++cc)
            hc[rr][cc] = acc[rr][cc] >= 0.f ? acc[rr][cc] : RRELU_SLOPE * acc[rr][cc];
    __syncthreads();

    // ---- phase 3: gate = sigmoid(hcur @ Wt + b); out = g*hcur + (1-g)*his ----
    stage_w(Wt, sW, tid);
    #pragma unroll
    for (int rr = 0; rr < 4; ++rr)
        *(float4*)(sIn + (r0 + rr) * LDS_STRIDE + j0) =
            make_float4(hc[rr][0], hc[rr][1], hc[rr][2], hc[rr][3]);
    __syncthreads();

    const float b0 = bias[j0 + 0], b1 = bias[j0 + 1],
                b2 = bias[j0 + 2], b3 = bias[j0 + 3];
    float acc2[4][4];
    #pragma unroll
    for (int rr = 0; rr < 4; ++rr) {
        acc2[rr][0] = b0; acc2[rr][1] = b1; acc2[rr][2] = b2; acc2[rr][3] = b3;
    }
    mm_tile(sW, sIn, r0, j0, acc2);

    #pragma unroll
    for (int rr = 0; rr < 4; ++rr) {
        const int row = row0 + r0 + rr;
        const float4 hv = *(const float4*)(his + (size_t)row * HD + j0);
        const float g0 = 1.f / (1.f + __expf(-acc2[rr][0]));
        const float g1 = 1.f / (1.f + __expf(-acc2[rr][1]));
        const float g2 = 1.f / (1.f + __expf(-acc2[rr][2]));
        const float g3 = 1.f / (1.f + __expf(-acc2[rr][3]));
        float4 o;
        o.x = g0 * hc[rr][0] + (1.f - g0) * hv.x;
        o.y = g1 * hc[rr][1] + (1.f - g1) * hv.y;
        o.z = g2 * hc[rr][2] + (1.f - g2) * hv.z;
        o.w = g3 * hc[rr][3] + (1.f - g3) * hv.w;
        *(float4*)(io + (size_t)row * HD + j0) = o;
    }
}

// ---------- launch ----------
extern "C" void kernel_launch(void* const* d_in, const int* in_sizes, int n_in,
                              void* d_out, int out_size, void* d_ws, size_t ws_size,
                              hipStream_t stream) {
    const float* ent   = (const float*)d_in[0];
    const float* rel   = (const float*)d_in[1];
    const float* his   = (const float*)d_in[2];
    const float* Wn    = (const float*)d_in[3];
    const float* Ws    = (const float*)d_in[4];
    const float* Wt    = (const float*)d_in[5];
    const float* bias  = (const float*)d_in[6];
    const float* enorm = (const float*)d_in[7];
    const int* src = (const int*)d_in[8];
    const int* dst = (const int*)d_in[9];
    const int* ety = (const int*)d_in[10];
    float* out = (float*)d_out;

    // workspace layout: invn[NPAD] f32 | cnt[NPAD] | offs[NPAD] | cur[NPAD] |
    //                   bsum[512] | perm[2M]   (total ~9.6 MB; R2 proved ws>=51.6MB)
    char* p = (char*)d_ws;
    float* invn = (float*)p;            p += (size_t)NPAD * 4;
    int*   cnt  = (int*)p;              p += (size_t)NPAD * 4;
    int*   offs = (int*)p;              p += (size_t)NPAD * 4;
    int*   cur  = (int*)p;              p += (size_t)NPAD * 4;
    int*   bsum = (int*)p;              p += 512 * 4;
    int*   perm = (int*)p;

    hipMemsetAsync(cnt, 0, (size_t)NPAD * 4, stream);
    norm_kernel<<<(NUM_ENTS + 3) / 4, 256, 0, stream>>>(ent, invn);
    hist_kernel<<<2048, 256, 0, stream>>>(dst, cnt);
    scan1_kernel<<<NBLK, 256, 0, stream>>>(cnt, offs, bsum);
    scan2_kernel<<<1, 512, 0, stream>>>(bsum);
    scan3_kernel<<<NBLK, 256, 0, stream>>>(offs, bsum, cur);
    permute_kernel<<<2048, 256, 0, stream>>>(dst, cur, perm);
    gather_kernel<<<(NUM_ENTS + 3) / 4, 256, 0, stream>>>(
        ent, rel, invn, enorm, src, ety, offs, perm, out /* S lives in d_out */);
    fused_kernel<<<NUM_ENTS / TM, 256, 0, stream>>>(      // 3125 full tiles
        out, ent, invn, Wn, Ws, Wt, bias, his);
}

// Round 4
// 713.557 us; speedup vs baseline: 2.7619x; 1.2086x over previous
//
#include <hip/hip_runtime.h>
#include <math.h>

#define NUM_ENTS   100000
#define HD         128
#define NUM_EDGES  2000000
#define NUM_RELS2  1000
#define RRELU_SLOPE 0.22916666666666666f
#define NBLK 391                 // ceil(100000/256)
#define NPAD (NBLK * 256)        // 100096 padded counter range

typedef __attribute__((ext_vector_type(8))) short bf16x8;
typedef __attribute__((ext_vector_type(4))) float f32x4;

// ---------- bf16 helpers ----------
__device__ __forceinline__ float bf2f(unsigned short h) {
    union { unsigned int u; float f; } v;
    v.u = ((unsigned int)h) << 16;
    return v.f;
}
__device__ __forceinline__ void unpack2(unsigned int u, float& lo, float& hi) {
    union { unsigned int u; float f; } a, b;
    a.u = u << 16;          // low ushort = element c
    b.u = u & 0xffff0000u;  // high ushort = element c+1
    lo = a.f; hi = b.f;
}
__device__ __forceinline__ unsigned short f2bf(float f) {
    union { float f; unsigned int u; } v; v.f = f;
    unsigned int r = 0x7fffu + ((v.u >> 16) & 1u);  // RNE
    return (unsigned short)((v.u + r) >> 16);
}

// ---------- 1. prep: hb = bf16(l2_normalize(ent)) ----------
__global__ void __launch_bounds__(256)
prep_kernel(const float* __restrict__ ent, unsigned short* __restrict__ hb) {
    const int wid  = threadIdx.x >> 6;
    const int lane = threadIdx.x & 63;
    const int row  = blockIdx.x * 4 + wid;
    if (row >= NUM_ENTS) return;
    const float2 v = *(const float2*)(ent + (size_t)row * HD + lane * 2);
    float ss = v.x * v.x + v.y * v.y;
    #pragma unroll
    for (int m = 1; m < 64; m <<= 1) ss += __shfl_xor(ss, m, 64);
    const float inv = 1.0f / fmaxf(sqrtf(ss), 1e-12f);
    const unsigned int o = (unsigned int)f2bf(v.x * inv) |
                           ((unsigned int)f2bf(v.y * inv) << 16);
    *(unsigned int*)(hb + (size_t)row * HD + lane * 2) = o;
}

// ---------- 1b. rel -> bf16 ----------
__global__ void __launch_bounds__(256)
relpack_kernel(const float* __restrict__ rel, unsigned short* __restrict__ rb) {
    const int i = blockIdx.x * 256 + threadIdx.x;   // float4 chunks
    if (i >= NUM_RELS2 * HD / 4) return;
    const float4 v = ((const float4*)rel)[i];
    ushort4 o;
    o.x = f2bf(v.x); o.y = f2bf(v.y); o.z = f2bf(v.z); o.w = f2bf(v.w);
    ((ushort4*)rb)[i] = o;
}

// ---------- 1c. pack 3 weights into per-lane MFMA B-fragment layout ----------
// frag index f = w*32 + t*4 + kt ; element: B[k0 + quad*8 + j][t*16 + (lane&15)]
__global__ void __launch_bounds__(64)
wpack_kernel(const float* __restrict__ Wn, const float* __restrict__ Ws,
             const float* __restrict__ Wt, unsigned short* __restrict__ Wp) {
    const int blk = blockIdx.x;            // 0..95
    const int w = blk >> 5, rem = blk & 31, t = rem >> 2, kt = rem & 3;
    const float* W = (w == 0) ? Wn : (w == 1) ? Ws : Wt;
    const int lane = threadIdx.x;
    const int n  = t * 16 + (lane & 15);
    const int k0 = kt * 32 + (lane >> 4) * 8;
    unsigned short tmp[8];
    #pragma unroll
    for (int j = 0; j < 8; ++j) tmp[j] = f2bf(W[(size_t)(k0 + j) * HD + n]);
    unsigned short* d = Wp + ((size_t)blk * 64 + lane) * 8;
    *(ushort4*)(d + 0) = make_ushort4(tmp[0], tmp[1], tmp[2], tmp[3]);
    *(ushort4*)(d + 4) = make_ushort4(tmp[4], tmp[5], tmp[6], tmp[7]);
}

// ---------- 2. counting sort of edges by dst ----------
__global__ void __launch_bounds__(256)
hist_kernel(const int* __restrict__ dst, int* __restrict__ cnt) {
    for (int e = blockIdx.x * 256 + threadIdx.x; e < NUM_EDGES; e += gridDim.x * 256)
        atomicAdd(&cnt[dst[e]], 1);
}

__global__ void __launch_bounds__(256)
scan1_kernel(const int* __restrict__ cnt, int* __restrict__ offs, int* __restrict__ bsum) {
    __shared__ int tmp[256];
    const int t = threadIdx.x;
    const int i = blockIdx.x * 256 + t;
    const int v = cnt[i];
    tmp[t] = v;
    __syncthreads();
    #pragma unroll
    for (int d = 1; d < 256; d <<= 1) {
        const int a = (t >= d) ? tmp[t - d] : 0;
        __syncthreads();
        tmp[t] += a;
        __syncthreads();
    }
    offs[i] = tmp[t] - v;
    if (t == 255) bsum[blockIdx.x] = tmp[255];
}

__global__ void __launch_bounds__(512)
scan2_kernel(int* __restrict__ bsum) {
    __shared__ int tmp[512];
    const int t = threadIdx.x;
    const int v = (t < NBLK) ? bsum[t] : 0;
    tmp[t] = v;
    __syncthreads();
    #pragma unroll
    for (int d = 1; d < 512; d <<= 1) {
        const int a = (t >= d) ? tmp[t - d] : 0;
        __syncthreads();
        tmp[t] += a;
        __syncthreads();
    }
    if (t < NBLK) bsum[t] = tmp[t] - v;
}

__global__ void __launch_bounds__(256)
scan3_kernel(int* __restrict__ offs, const int* __restrict__ bsum, int* __restrict__ cur) {
    const int i = blockIdx.x * 256 + threadIdx.x;
    const int o = offs[i] + bsum[blockIdx.x];
    offs[i] = o;
    cur[i]  = o;
}

__global__ void __launch_bounds__(256)
permute_kernel(const int* __restrict__ dst, int* __restrict__ cur, int* __restrict__ perm) {
    for (int e = blockIdx.x * 256 + threadIdx.x; e < NUM_EDGES; e += gridDim.x * 256) {
        const int pos = atomicAdd(&cur[dst[e]], 1);
        perm[pos] = e;
    }
}

// ---------- 3. gather (bf16 tables, f32 accum, plain f32 store) ----------
__global__ void __launch_bounds__(256)
gather_kernel(const unsigned short* __restrict__ hb,
              const unsigned short* __restrict__ rb,
              const float* __restrict__ enorm,
              const int* __restrict__ src,
              const int* __restrict__ ety,
              const int* __restrict__ offs,
              const int* __restrict__ perm,
              float* __restrict__ S) {
    const int d = blockIdx.x * 4 + (threadIdx.x >> 6);
    if (d >= NUM_ENTS) return;
    const int lane = threadIdx.x & 63;
    const int beg = offs[d], end = offs[d + 1];
    float a0 = 0.f, a1 = 0.f;
    int i = beg;
    int e0 = (i < end) ? perm[i] : 0;
    while (i < end) {
        const int e = e0;
        if (i + 1 < end) e0 = perm[i + 1];
        const int s = src[e], t = ety[e];
        const float w = enorm[e];
        const unsigned int hv = *(const unsigned int*)(hb + (size_t)s * HD + lane * 2);
        const unsigned int rv = *(const unsigned int*)(rb + (size_t)t * HD + lane * 2);
        float h0, h1, r0, r1;
        unpack2(hv, h0, h1);
        unpack2(rv, r0, r1);
        a0 += (h0 + r0) * w;
        a1 += (h1 + r1) * w;
        ++i;
    }
    *(float2*)(S + (size_t)d * HD + lane * 2) = make_float2(a0, a1);
}

// ---------- 4. fused MFMA: hcur = S@Wn + h@Ws -> rrelu -> gate -> blend ----------
// Per block: 64 rows, 4 waves, 16 rows/wave. Wave-local only -> no barriers.
__global__ void __launch_bounds__(256)
fused_mfma(float* io,                        // aliased: S rows in, out rows out
           const unsigned short* __restrict__ hb,
           const unsigned short* __restrict__ Wp,
           const float* __restrict__ bias,
           const float* __restrict__ his) {
    __shared__ unsigned short tile[4][16 * 136];   // per-wave 16x128 bf16, pad 8
    const int tid = threadIdx.x;
    const int wv = tid >> 6, lane = tid & 63;
    const int m0 = blockIdx.x * 64 + wv * 16;
    if (m0 >= NUM_ENTS) return;
    const int rA = lane & 15, quad = lane >> 4;
    unsigned short* T = tile[wv];

    // stage S tile f32 -> bf16 LDS (wave covers its own 16 rows)
    #pragma unroll
    for (int i = 0; i < 8; ++i) {
        const int idx = i * 64 + lane;
        const int r = idx >> 5, c4 = idx & 31;
        const float4 v = ((const float4*)(io + (size_t)(m0 + r) * HD))[c4];
        ushort4 o;
        o.x = f2bf(v.x); o.y = f2bf(v.y); o.z = f2bf(v.z); o.w = f2bf(v.w);
        *(ushort4*)(T + r * 136 + c4 * 4) = o;
    }

    const bf16x8* WF = (const bf16x8*)Wp;
    f32x4 acc[8];
    #pragma unroll
    for (int t = 0; t < 8; ++t) acc[t] = (f32x4)0.f;

    // phase 1: A = S (LDS), B = Wn ; phase 2: A = h_norm (global hb), B = Ws
    #pragma unroll
    for (int ph = 0; ph < 2; ++ph) {
        bf16x8 a[4];
        if (ph == 0) {
            #pragma unroll
            for (int kt = 0; kt < 4; ++kt)
                a[kt] = *(const bf16x8*)(T + rA * 136 + kt * 32 + quad * 8);
        } else {
            const unsigned short* base = hb + (size_t)(m0 + rA) * HD + quad * 8;
            #pragma unroll
            for (int kt = 0; kt < 4; ++kt)
                a[kt] = *(const bf16x8*)(base + kt * 32);
        }
        #pragma unroll
        for (int t = 0; t < 8; ++t) {
            #pragma unroll
            for (int kt = 0; kt < 4; ++kt) {
                const bf16x8 b = WF[(size_t)(ph * 32 + t * 4 + kt) * 64 + lane];
                acc[t] = __builtin_amdgcn_mfma_f32_16x16x32_bf16(a[kt], b, acc[t], 0, 0, 0);
            }
        }
    }

    // rrelu (C layout: col = t*16 + (lane&15), row = quad*4 + r)
    #pragma unroll
    for (int t = 0; t < 8; ++t)
        #pragma unroll
        for (int r = 0; r < 4; ++r)
            acc[t][r] = acc[t][r] >= 0.f ? acc[t][r] : RRELU_SLOPE * acc[t][r];

    // transpose hcur C-layout -> A-layout via wave-local LDS (bf16)
    #pragma unroll
    for (int t = 0; t < 8; ++t)
        #pragma unroll
        for (int r = 0; r < 4; ++r)
            T[(quad * 4 + r) * 136 + t * 16 + rA] = f2bf(acc[t][r]);

    // phase 3: gate GEMM (B = Wt), bias init
    bf16x8 a3[4];
    #pragma unroll
    for (int kt = 0; kt < 4; ++kt)
        a3[kt] = *(const bf16x8*)(T + rA * 136 + kt * 32 + quad * 8);

    f32x4 acc2[8];
    #pragma unroll
    for (int t = 0; t < 8; ++t) {
        const float bn = bias[t * 16 + rA];
        acc2[t] = (f32x4){bn, bn, bn, bn};
    }
    #pragma unroll
    for (int t = 0; t < 8; ++t) {
        #pragma unroll
        for (int kt = 0; kt < 4; ++kt) {
            const bf16x8 b = WF[(size_t)(64 + t * 4 + kt) * 64 + lane];
            acc2[t] = __builtin_amdgcn_mfma_f32_16x16x32_bf16(a3[kt], b, acc2[t], 0, 0, 0);
        }
    }

    // epilogue: sigmoid gate, blend with his, store (wave's own 16 rows)
    #pragma unroll
    for (int t = 0; t < 8; ++t) {
        const int col = t * 16 + rA;
        #pragma unroll
        for (int r = 0; r < 4; ++r) {
            const size_t row = (size_t)(m0 + quad * 4 + r);
            const float g = 1.f / (1.f + __expf(-acc2[t][r]));
            const float h = his[row * HD + col];
            io[row * HD + col] = g * acc[t][r] + (1.f - g) * h;
        }
    }
}

// ---------- launch ----------
extern "C" void kernel_launch(void* const* d_in, const int* in_sizes, int n_in,
                              void* d_out, int out_size, void* d_ws, size_t ws_size,
                              hipStream_t stream) {
    const float* ent   = (const float*)d_in[0];
    const float* rel   = (const float*)d_in[1];
    const float* his   = (const float*)d_in[2];
    const float* Wn    = (const float*)d_in[3];
    const float* Ws    = (const float*)d_in[4];
    const float* Wt    = (const float*)d_in[5];
    const float* bias  = (const float*)d_in[6];
    const float* enorm = (const float*)d_in[7];
    const int* src = (const int*)d_in[8];
    const int* dst = (const int*)d_in[9];
    const int* ety = (const int*)d_in[10];
    float* out = (float*)d_out;

    // ws: hb 25.6MB | rb 256KB | Wp 96KB | cnt/offs/cur 1.2MB | bsum | perm 8MB  (~35MB)
    char* p = (char*)d_ws;
    unsigned short* hb = (unsigned short*)p;  p += (size_t)NUM_ENTS * HD * 2;
    unsigned short* rb = (unsigned short*)p;  p += (size_t)NUM_RELS2 * HD * 2;
    unsigned short* Wp = (unsigned short*)p;  p += (size_t)96 * 64 * 8 * 2;
    int* cnt  = (int*)p;                      p += (size_t)NPAD * 4;
    int* offs = (int*)p;                      p += (size_t)NPAD * 4;
    int* cur  = (int*)p;                      p += (size_t)NPAD * 4;
    int* bsum = (int*)p;                      p += 512 * 4;
    int* perm = (int*)p;

    hipMemsetAsync(cnt, 0, (size_t)NPAD * 4, stream);
    prep_kernel<<<(NUM_ENTS + 3) / 4, 256, 0, stream>>>(ent, hb);
    relpack_kernel<<<(NUM_RELS2 * HD / 4 + 255) / 256, 256, 0, stream>>>(rel, rb);
    wpack_kernel<<<96, 64, 0, stream>>>(Wn, Ws, Wt, Wp);
    hist_kernel<<<2048, 256, 0, stream>>>(dst, cnt);
    scan1_kernel<<<NBLK, 256, 0, stream>>>(cnt, offs, bsum);
    scan2_kernel<<<1, 512, 0, stream>>>(bsum);
    scan3_kernel<<<NBLK, 256, 0, stream>>>(offs, bsum, cur);
    permute_kernel<<<2048, 256, 0, stream>>>(dst, cur, perm);
    gather_kernel<<<(NUM_ENTS + 3) / 4, 256, 0, stream>>>(
        hb, rb, enorm, src, ety, offs, perm, out /* S lives in d_out */);
    fused_mfma<<<(NUM_ENTS + 63) / 64, 256, 0, stream>>>(out, hb, Wp, bias, his);
}

// Round 5
// 639.178 us; speedup vs baseline: 3.0833x; 1.1164x over previous
//
#include <hip/hip_runtime.h>
#include <math.h>

#define NUM_ENTS   100000
#define HD         128
#define NUM_EDGES  2000000
#define NUM_RELS2  1000
#define RRELU_SLOPE 0.22916666666666666f
#define NBLK 391                 // ceil(100000/256)
#define NPAD (NBLK * 256)        // 100096 padded counter range

typedef __attribute__((ext_vector_type(8))) short bf16x8;
typedef __attribute__((ext_vector_type(4))) float f32x4;

// ---------- bf16 helpers ----------
__device__ __forceinline__ float bf2f(unsigned short h) {
    union { unsigned int u; float f; } v;
    v.u = ((unsigned int)h) << 16;
    return v.f;
}
__device__ __forceinline__ void unpack2(unsigned int u, float& lo, float& hi) {
    union { unsigned int u; float f; } a, b;
    a.u = u << 16;          // low ushort = element c
    b.u = u & 0xffff0000u;  // high ushort = element c+1
    lo = a.f; hi = b.f;
}
__device__ __forceinline__ unsigned short f2bf(float f) {
    union { float f; unsigned int u; } v; v.f = f;
    unsigned int r = 0x7fffu + ((v.u >> 16) & 1u);  // RNE
    return (unsigned short)((v.u + r) >> 16);
}

// ---------- 1. prep: hb = bf16(l2_normalize(ent)) ----------
__global__ void __launch_bounds__(256)
prep_kernel(const float* __restrict__ ent, unsigned short* __restrict__ hb) {
    const int wid  = threadIdx.x >> 6;
    const int lane = threadIdx.x & 63;
    const int row  = blockIdx.x * 4 + wid;
    if (row >= NUM_ENTS) return;
    const float2 v = *(const float2*)(ent + (size_t)row * HD + lane * 2);
    float ss = v.x * v.x + v.y * v.y;
    #pragma unroll
    for (int m = 1; m < 64; m <<= 1) ss += __shfl_xor(ss, m, 64);
    const float inv = 1.0f / fmaxf(sqrtf(ss), 1e-12f);
    const unsigned int o = (unsigned int)f2bf(v.x * inv) |
                           ((unsigned int)f2bf(v.y * inv) << 16);
    *(unsigned int*)(hb + (size_t)row * HD + lane * 2) = o;
}

// ---------- 1b. rel -> bf16 ----------
__global__ void __launch_bounds__(256)
relpack_kernel(const float* __restrict__ rel, unsigned short* __restrict__ rb) {
    const int i = blockIdx.x * 256 + threadIdx.x;   // float4 chunks
    if (i >= NUM_RELS2 * HD / 4) return;
    const float4 v = ((const float4*)rel)[i];
    ushort4 o;
    o.x = f2bf(v.x); o.y = f2bf(v.y); o.z = f2bf(v.z); o.w = f2bf(v.w);
    ((ushort4*)rb)[i] = o;
}

// ---------- 1c. pack 3 weights into per-lane MFMA B-fragment layout ----------
// frag index f = w*32 + t*4 + kt ; element: B[k0 + quad*8 + j][t*16 + (lane&15)]
__global__ void __launch_bounds__(64)
wpack_kernel(const float* __restrict__ Wn, const float* __restrict__ Ws,
             const float* __restrict__ Wt, unsigned short* __restrict__ Wp) {
    const int blk = blockIdx.x;            // 0..95
    const int w = blk >> 5, rem = blk & 31, t = rem >> 2, kt = rem & 3;
    const float* W = (w == 0) ? Wn : (w == 1) ? Ws : Wt;
    const int lane = threadIdx.x;
    const int n  = t * 16 + (lane & 15);
    const int k0 = kt * 32 + (lane >> 4) * 8;
    unsigned short tmp[8];
    #pragma unroll
    for (int j = 0; j < 8; ++j) tmp[j] = f2bf(W[(size_t)(k0 + j) * HD + n]);
    unsigned short* d = Wp + ((size_t)blk * 64 + lane) * 8;
    *(ushort4*)(d + 0) = make_ushort4(tmp[0], tmp[1], tmp[2], tmp[3]);
    *(ushort4*)(d + 4) = make_ushort4(tmp[4], tmp[5], tmp[6], tmp[7]);
}

// ---------- 2. counting sort of edges by dst ----------
__global__ void __launch_bounds__(256)
hist_kernel(const int* __restrict__ dst, int* __restrict__ cnt) {
    for (int e = blockIdx.x * 256 + threadIdx.x; e < NUM_EDGES; e += gridDim.x * 256)
        atomicAdd(&cnt[dst[e]], 1);
}

__global__ void __launch_bounds__(256)
scan1_kernel(const int* __restrict__ cnt, int* __restrict__ offs, int* __restrict__ bsum) {
    __shared__ int tmp[256];
    const int t = threadIdx.x;
    const int i = blockIdx.x * 256 + t;
    const int v = cnt[i];
    tmp[t] = v;
    __syncthreads();
    #pragma unroll
    for (int d = 1; d < 256; d <<= 1) {
        const int a = (t >= d) ? tmp[t - d] : 0;
        __syncthreads();
        tmp[t] += a;
        __syncthreads();
    }
    offs[i] = tmp[t] - v;
    if (t == 255) bsum[blockIdx.x] = tmp[255];
}

__global__ void __launch_bounds__(512)
scan2_kernel(int* __restrict__ bsum) {
    __shared__ int tmp[512];
    const int t = threadIdx.x;
    const int v = (t < NBLK) ? bsum[t] : 0;
    tmp[t] = v;
    __syncthreads();
    #pragma unroll
    for (int d = 1; d < 512; d <<= 1) {
        const int a = (t >= d) ? tmp[t - d] : 0;
        __syncthreads();
        tmp[t] += a;
        __syncthreads();
    }
    if (t < NBLK) bsum[t] = tmp[t] - v;
}

__global__ void __launch_bounds__(256)
scan3_kernel(int* __restrict__ offs, const int* __restrict__ bsum, int* __restrict__ cur) {
    const int i = blockIdx.x * 256 + threadIdx.x;
    const int o = offs[i] + bsum[blockIdx.x];
    offs[i] = o;
    cur[i]  = o;
}

// ---------- 2e. permute + record build: recs[pos] = {src | ety<<17, w} ----------
__global__ void __launch_bounds__(256)
permute_kernel(const int* __restrict__ dst, const int* __restrict__ src,
               const int* __restrict__ ety, const float* __restrict__ enorm,
               int* __restrict__ cur, uint2* __restrict__ recs) {
    for (int e = blockIdx.x * 256 + threadIdx.x; e < NUM_EDGES; e += gridDim.x * 256) {
        const int pos = atomicAdd(&cur[dst[e]], 1);
        uint2 rc;
        rc.x = (unsigned int)src[e] | ((unsigned int)ety[e] << 17);
        rc.y = __float_as_uint(enorm[e]);
        recs[pos] = rc;
    }
}

// ---------- 3. gather (sorted records, depth-2 pipelined hb loads) ----------
__global__ void __launch_bounds__(256)
gather_kernel(const unsigned short* __restrict__ hb,
              const unsigned short* __restrict__ rb,
              const int* __restrict__ offs,
              const uint2* __restrict__ recs,
              float* __restrict__ S) {
    const int d = blockIdx.x * 4 + (threadIdx.x >> 6);
    if (d >= NUM_ENTS) return;
    const int lane = threadIdx.x & 63;
    const int beg = offs[d], end = offs[d + 1];
    float a0 = 0.f, a1 = 0.f;

    unsigned int hv0 = 0, rv0 = 0, hv1 = 0, rv1 = 0;
    float w0 = 0.f, w1 = 0.f;

    if (beg < end) {
        const uint2 rc = recs[beg];
        w0  = __uint_as_float(rc.y);
        hv0 = *(const unsigned int*)(hb + (size_t)(rc.x & 0x1FFFFu) * HD + lane * 2);
        rv0 = *(const unsigned int*)(rb + (size_t)(rc.x >> 17) * HD + lane * 2);
    }
    if (beg + 1 < end) {
        const uint2 rc = recs[beg + 1];
        w1  = __uint_as_float(rc.y);
        hv1 = *(const unsigned int*)(hb + (size_t)(rc.x & 0x1FFFFu) * HD + lane * 2);
        rv1 = *(const unsigned int*)(rb + (size_t)(rc.x >> 17) * HD + lane * 2);
    }
    for (int i = beg; i < end; ++i) {
        unsigned int hv2 = 0, rv2 = 0; float w2 = 0.f;
        if (i + 2 < end) {
            const uint2 rc = recs[i + 2];
            w2  = __uint_as_float(rc.y);
            hv2 = *(const unsigned int*)(hb + (size_t)(rc.x & 0x1FFFFu) * HD + lane * 2);
            rv2 = *(const unsigned int*)(rb + (size_t)(rc.x >> 17) * HD + lane * 2);
        }
        float h0, h1, r0, r1;
        unpack2(hv0, h0, h1);
        unpack2(rv0, r0, r1);
        a0 += (h0 + r0) * w0;
        a1 += (h1 + r1) * w0;
        hv0 = hv1; rv0 = rv1; w0 = w1;
        hv1 = hv2; rv1 = rv2; w1 = w2;
    }
    *(float2*)(S + (size_t)d * HD + lane * 2) = make_float2(a0, a1);
}

// ---------- 4. fused MFMA: hcur = S@Wn + h@Ws -> rrelu -> gate -> blend ----------
// Per block: 64 rows, 4 waves, 16 rows/wave. Wave-local only -> no barriers.
__global__ void __launch_bounds__(256)
fused_mfma(float* io,                        // aliased: S rows in, out rows out
           const unsigned short* __restrict__ hb,
           const unsigned short* __restrict__ Wp,
           const float* __restrict__ bias,
           const float* __restrict__ his) {
    __shared__ unsigned short tile[4][16 * 136];   // per-wave 16x128 bf16, pad 8
    const int tid = threadIdx.x;
    const int wv = tid >> 6, lane = tid & 63;
    const int m0 = blockIdx.x * 64 + wv * 16;
    if (m0 >= NUM_ENTS) return;
    const int rA = lane & 15, quad = lane >> 4;
    unsigned short* T = tile[wv];

    // stage S tile f32 -> bf16 LDS (wave covers its own 16 rows)
    #pragma unroll
    for (int i = 0; i < 8; ++i) {
        const int idx = i * 64 + lane;
        const int r = idx >> 5, c4 = idx & 31;
        const float4 v = ((const float4*)(io + (size_t)(m0 + r) * HD))[c4];
        ushort4 o;
        o.x = f2bf(v.x); o.y = f2bf(v.y); o.z = f2bf(v.z); o.w = f2bf(v.w);
        *(ushort4*)(T + r * 136 + c4 * 4) = o;
    }

    const bf16x8* WF = (const bf16x8*)Wp;
    f32x4 acc[8];
    #pragma unroll
    for (int t = 0; t < 8; ++t) acc[t] = (f32x4)0.f;

    // phase 1: A = S (LDS), B = Wn ; phase 2: A = h_norm (global hb), B = Ws
    #pragma unroll
    for (int ph = 0; ph < 2; ++ph) {
        bf16x8 a[4];
        if (ph == 0) {
            #pragma unroll
            for (int kt = 0; kt < 4; ++kt)
                a[kt] = *(const bf16x8*)(T + rA * 136 + kt * 32 + quad * 8);
        } else {
            const unsigned short* base = hb + (size_t)(m0 + rA) * HD + quad * 8;
            #pragma unroll
            for (int kt = 0; kt < 4; ++kt)
                a[kt] = *(const bf16x8*)(base + kt * 32);
        }
        #pragma unroll
        for (int t = 0; t < 8; ++t) {
            #pragma unroll
            for (int kt = 0; kt < 4; ++kt) {
                const bf16x8 b = WF[(size_t)(ph * 32 + t * 4 + kt) * 64 + lane];
                acc[t] = __builtin_amdgcn_mfma_f32_16x16x32_bf16(a[kt], b, acc[t], 0, 0, 0);
            }
        }
    }

    // rrelu (C layout: col = t*16 + (lane&15), row = quad*4 + r)
    #pragma unroll
    for (int t = 0; t < 8; ++t)
        #pragma unroll
        for (int r = 0; r < 4; ++r)
            acc[t][r] = acc[t][r] >= 0.f ? acc[t][r] : RRELU_SLOPE * acc[t][r];

    // transpose hcur C-layout -> A-layout via wave-local LDS (bf16)
    #pragma unroll
    for (int t = 0; t < 8; ++t)
        #pragma unroll
        for (int r = 0; r < 4; ++r)
            T[(quad * 4 + r) * 136 + t * 16 + rA] = f2bf(acc[t][r]);

    // phase 3: gate GEMM (B = Wt), bias init
    bf16x8 a3[4];
    #pragma unroll
    for (int kt = 0; kt < 4; ++kt)
        a3[kt] = *(const bf16x8*)(T + rA * 136 + kt * 32 + quad * 8);

    f32x4 acc2[8];
    #pragma unroll
    for (int t = 0; t < 8; ++t) {
        const float bn = bias[t * 16 + rA];
        acc2[t] = (f32x4){bn, bn, bn, bn};
    }
    #pragma unroll
    for (int t = 0; t < 8; ++t) {
        #pragma unroll
        for (int kt = 0; kt < 4; ++kt) {
            const bf16x8 b = WF[(size_t)(64 + t * 4 + kt) * 64 + lane];
            acc2[t] = __builtin_amdgcn_mfma_f32_16x16x32_bf16(a3[kt], b, acc2[t], 0, 0, 0);
        }
    }

    // epilogue: sigmoid gate, blend with his, store (wave's own 16 rows)
    #pragma unroll
    for (int t = 0; t < 8; ++t) {
        const int col = t * 16 + rA;
        #pragma unroll
        for (int r = 0; r < 4; ++r) {
            const size_t row = (size_t)(m0 + quad * 4 + r);
            const float g = 1.f / (1.f + __expf(-acc2[t][r]));
            const float h = his[row * HD + col];
            io[row * HD + col] = g * acc[t][r] + (1.f - g) * h;
        }
    }
}

// ---------- launch ----------
extern "C" void kernel_launch(void* const* d_in, const int* in_sizes, int n_in,
                              void* d_out, int out_size, void* d_ws, size_t ws_size,
                              hipStream_t stream) {
    const float* ent   = (const float*)d_in[0];
    const float* rel   = (const float*)d_in[1];
    const float* his   = (const float*)d_in[2];
    const float* Wn    = (const float*)d_in[3];
    const float* Ws    = (const float*)d_in[4];
    const float* Wt    = (const float*)d_in[5];
    const float* bias  = (const float*)d_in[6];
    const float* enorm = (const float*)d_in[7];
    const int* src = (const int*)d_in[8];
    const int* dst = (const int*)d_in[9];
    const int* ety = (const int*)d_in[10];
    float* out = (float*)d_out;

    // ws: hb 25.6MB | rb 256KB | Wp 96KB | cnt/offs/cur 1.2MB | bsum | recs 16MB (~43MB)
    char* p = (char*)d_ws;
    unsigned short* hb = (unsigned short*)p;  p += (size_t)NUM_ENTS * HD * 2;
    unsigned short* rb = (unsigned short*)p;  p += (size_t)NUM_RELS2 * HD * 2;
    unsigned short* Wp = (unsigned short*)p;  p += (size_t)96 * 64 * 8 * 2;
    int* cnt  = (int*)p;                      p += (size_t)NPAD * 4;
    int* offs = (int*)p;                      p += (size_t)NPAD * 4;
    int* cur  = (int*)p;                      p += (size_t)NPAD * 4;
    int* bsum = (int*)p;                      p += 512 * 4;
    uint2* recs = (uint2*)p;

    hipMemsetAsync(cnt, 0, (size_t)NPAD * 4, stream);
    prep_kernel<<<(NUM_ENTS + 3) / 4, 256, 0, stream>>>(ent, hb);
    relpack_kernel<<<(NUM_RELS2 * HD / 4 + 255) / 256, 256, 0, stream>>>(rel, rb);
    wpack_kernel<<<96, 64, 0, stream>>>(Wn, Ws, Wt, Wp);
    hist_kernel<<<2048, 256, 0, stream>>>(dst, cnt);
    scan1_kernel<<<NBLK, 256, 0, stream>>>(cnt, offs, bsum);
    scan2_kernel<<<1, 512, 0, stream>>>(bsum);
    scan3_kernel<<<NBLK, 256, 0, stream>>>(offs, bsum, cur);
    permute_kernel<<<2048, 256, 0, stream>>>(dst, src, ety, enorm, cur, recs);
    gather_kernel<<<(NUM_ENTS + 3) / 4, 256, 0, stream>>>(
        hb, rb, offs, recs, out /* S lives in d_out */);
    fused_mfma<<<(NUM_ENTS + 63) / 64, 256, 0, stream>>>(out, hb, Wp, bias, his);
}

// Round 6
// 451.441 us; speedup vs baseline: 4.3656x; 1.4159x over previous
//
#include <hip/hip_runtime.h>
#include <math.h>

#define NUM_ENTS   100000
#define HD         128
#define NUM_EDGES  2000000
#define NUM_RELS2  1000
#define RRELU_SLOPE 0.22916666666666666f
#define NBLK 391                 // ceil(100000/256)
#define NPAD (NBLK * 256)        // 100096 padded counter range

// setup_kernel section boundaries (exact covers, no remainders)
#define SB_CNT 391               // zero cnt: 391*256 = 100096
#define SB_HB  25000             // prep hb: 25000*4 rows = 100000
#define SB_RB  125               // relpack: 125*256 = 32000 float4 chunks
#define SB_WP  24                // wpack: 24*4 = 96 sub-blocks
#define SB_TOTAL (SB_CNT + SB_HB + SB_RB + SB_WP)   // 25540

typedef __attribute__((ext_vector_type(8))) short bf16x8;
typedef __attribute__((ext_vector_type(4))) float f32x4;

// ---------- bf16 helpers ----------
__device__ __forceinline__ float bf2f(unsigned short h) {
    union { unsigned int u; float f; } v;
    v.u = ((unsigned int)h) << 16;
    return v.f;
}
__device__ __forceinline__ void unpack2(unsigned int u, float& lo, float& hi) {
    union { unsigned int u; float f; } a, b;
    a.u = u << 16;          // low ushort = element c
    b.u = u & 0xffff0000u;  // high ushort = element c+1
    lo = a.f; hi = b.f;
}
__device__ __forceinline__ unsigned short f2bf(float f) {
    union { float f; unsigned int u; } v; v.f = f;
    unsigned int r = 0x7fffu + ((v.u >> 16) & 1u);  // RNE
    return (unsigned short)((v.u + r) >> 16);
}

// ---------- 1. setup: zero cnt | hb = bf16(l2norm(ent)) | rb | Wp ----------
__global__ void __launch_bounds__(256)
setup_kernel(const float* __restrict__ ent, const float* __restrict__ rel,
             const float* __restrict__ Wn, const float* __restrict__ Ws,
             const float* __restrict__ Wt,
             int* __restrict__ cnt, unsigned short* __restrict__ hb,
             unsigned short* __restrict__ rb, unsigned short* __restrict__ Wp) {
    const int bid = blockIdx.x, tid = threadIdx.x;
    if (bid < SB_CNT) {                                   // zero cnt
        cnt[bid * 256 + tid] = 0;
    } else if (bid < SB_CNT + SB_HB) {                    // hb
        const int row = (bid - SB_CNT) * 4 + (tid >> 6);
        const int lane = tid & 63;
        const float2 v = *(const float2*)(ent + (size_t)row * HD + lane * 2);
        float ss = v.x * v.x + v.y * v.y;
        #pragma unroll
        for (int m = 1; m < 64; m <<= 1) ss += __shfl_xor(ss, m, 64);
        const float inv = 1.0f / fmaxf(sqrtf(ss), 1e-12f);
        const unsigned int o = (unsigned int)f2bf(v.x * inv) |
                               ((unsigned int)f2bf(v.y * inv) << 16);
        *(unsigned int*)(hb + (size_t)row * HD + lane * 2) = o;
    } else if (bid < SB_CNT + SB_HB + SB_RB) {            // rb
        const int i = (bid - SB_CNT - SB_HB) * 256 + tid;
        const float4 v = ((const float4*)rel)[i];
        ushort4 o;
        o.x = f2bf(v.x); o.y = f2bf(v.y); o.z = f2bf(v.z); o.w = f2bf(v.w);
        ((ushort4*)rb)[i] = o;
    } else {                                              // Wp
        const int blk = (bid - SB_CNT - SB_HB - SB_RB) * 4 + (tid >> 6);
        const int lane = tid & 63;
        const int w = blk >> 5, rem = blk & 31, t = rem >> 2, kt = rem & 3;
        const float* W = (w == 0) ? Wn : (w == 1) ? Ws : Wt;
        const int n  = t * 16 + (lane & 15);
        const int k0 = kt * 32 + (lane >> 4) * 8;
        unsigned short tmp[8];
        #pragma unroll
        for (int j = 0; j < 8; ++j) tmp[j] = f2bf(W[(size_t)(k0 + j) * HD + n]);
        unsigned short* d = Wp + ((size_t)blk * 64 + lane) * 8;
        *(ushort4*)(d + 0) = make_ushort4(tmp[0], tmp[1], tmp[2], tmp[3]);
        *(ushort4*)(d + 4) = make_ushort4(tmp[4], tmp[5], tmp[6], tmp[7]);
    }
}

// ---------- 2. histogram + within-bucket position ----------
__global__ void __launch_bounds__(256)
hist_kernel(const int* __restrict__ dst, int* __restrict__ cnt, int* __restrict__ pos) {
    for (int e = blockIdx.x * 256 + threadIdx.x; e < NUM_EDGES; e += gridDim.x * 256)
        pos[e] = atomicAdd(&cnt[dst[e]], 1);
}

__global__ void __launch_bounds__(256)
scan1_kernel(const int* __restrict__ cnt, int* __restrict__ offs, int* __restrict__ bsum) {
    __shared__ int tmp[256];
    const int t = threadIdx.x;
    const int i = blockIdx.x * 256 + t;
    const int v = cnt[i];
    tmp[t] = v;
    __syncthreads();
    #pragma unroll
    for (int d = 1; d < 256; d <<= 1) {
        const int a = (t >= d) ? tmp[t - d] : 0;
        __syncthreads();
        tmp[t] += a;
        __syncthreads();
    }
    offs[i] = tmp[t] - v;
    if (t == 255) bsum[blockIdx.x] = tmp[255];
}

__global__ void __launch_bounds__(512)
scan2_kernel(int* __restrict__ bsum) {
    __shared__ int tmp[512];
    const int t = threadIdx.x;
    const int v = (t < NBLK) ? bsum[t] : 0;
    tmp[t] = v;
    __syncthreads();
    #pragma unroll
    for (int d = 1; d < 512; d <<= 1) {
        const int a = (t >= d) ? tmp[t - d] : 0;
        __syncthreads();
        tmp[t] += a;
        __syncthreads();
    }
    if (t < NBLK) bsum[t] = tmp[t] - v;
}

__global__ void __launch_bounds__(256)
scan3_kernel(int* __restrict__ offs, const int* __restrict__ bsum) {
    const int i = blockIdx.x * 256 + threadIdx.x;
    offs[i] += bsum[blockIdx.x];
}

// ---------- 3. permute (pure scatter, no atomics): recs[offs[d]+pos] ----------
__global__ void __launch_bounds__(256)
permute_kernel(const int* __restrict__ dst, const int* __restrict__ src,
               const int* __restrict__ ety, const float* __restrict__ enorm,
               const int* __restrict__ offs, const int* __restrict__ pos,
               uint2* __restrict__ recs) {
    for (int e = blockIdx.x * 256 + threadIdx.x; e < NUM_EDGES; e += gridDim.x * 256) {
        const int p = offs[dst[e]] + pos[e];
        uint2 rc;
        rc.x = (unsigned int)src[e] | ((unsigned int)ety[e] << 17);
        rc.y = __float_as_uint(enorm[e]);
        recs[p] = rc;
    }
}

// ---------- 4. gather: 4 dsts per wave, 16 lanes/dst, dwordx4 rows ----------
__device__ __forceinline__ void accum8(float* acc, uint4 hv, uint4 rv, float w) {
    float h0, h1, r0, r1;
    unpack2(hv.x, h0, h1); unpack2(rv.x, r0, r1);
    acc[0] += (h0 + r0) * w; acc[1] += (h1 + r1) * w;
    unpack2(hv.y, h0, h1); unpack2(rv.y, r0, r1);
    acc[2] += (h0 + r0) * w; acc[3] += (h1 + r1) * w;
    unpack2(hv.z, h0, h1); unpack2(rv.z, r0, r1);
    acc[4] += (h0 + r0) * w; acc[5] += (h1 + r1) * w;
    unpack2(hv.w, h0, h1); unpack2(rv.w, r0, r1);
    acc[6] += (h0 + r0) * w; acc[7] += (h1 + r1) * w;
}

__global__ void __launch_bounds__(256)
gather_kernel(const unsigned short* __restrict__ hb,
              const unsigned short* __restrict__ rb,
              const int* __restrict__ offs,
              const uint2* __restrict__ recs,
              float* __restrict__ S) {
    const int tid = threadIdx.x;
    const int wv = tid >> 6, lane = tid & 63;
    const int grp = lane >> 4, sub = lane & 15;
    const int d = (blockIdx.x * 4 + wv) * 4 + grp;    // 16 dsts per block, exact
    const int beg = offs[d], end = offs[d + 1];
    int i = beg;
    float acc[8] = {0.f, 0.f, 0.f, 0.f, 0.f, 0.f, 0.f, 0.f};
    const unsigned short* hbp = hb + sub * 8;
    const unsigned short* rbp = rb + sub * 8;

    while (__any(i < end)) {
        const bool a0 = i < end, a1 = (i + 1) < end;
        const int j0 = min(i, NUM_EDGES - 1);
        const int j1 = min(i + 1, NUM_EDGES - 1);
        const uint2 rc0 = recs[j0];
        const uint2 rc1 = recs[j1];
        const float w0 = a0 ? __uint_as_float(rc0.y) : 0.f;
        const float w1 = a1 ? __uint_as_float(rc1.y) : 0.f;
        const uint4 hv0 = *(const uint4*)(hbp + (size_t)(rc0.x & 0x1FFFFu) * HD);
        const uint4 rv0 = *(const uint4*)(rbp + (size_t)(rc0.x >> 17) * HD);
        const uint4 hv1 = *(const uint4*)(hbp + (size_t)(rc1.x & 0x1FFFFu) * HD);
        const uint4 rv1 = *(const uint4*)(rbp + (size_t)(rc1.x >> 17) * HD);
        accum8(acc, hv0, rv0, w0);
        accum8(acc, hv1, rv1, w1);
        i += 2;
    }
    float* o = S + (size_t)d * HD + sub * 8;
    *(float4*)(o + 0) = make_float4(acc[0], acc[1], acc[2], acc[3]);
    *(float4*)(o + 4) = make_float4(acc[4], acc[5], acc[6], acc[7]);
}

// ---------- 5. fused MFMA: hcur = S@Wn + h@Ws -> rrelu -> gate -> blend ----------
// Per block: 64 rows, 4 waves, 16 rows/wave. Wave-local only -> no barriers.
__global__ void __launch_bounds__(256)
fused_mfma(float* io,                        // aliased: S rows in, out rows out
           const unsigned short* __restrict__ hb,
           const unsigned short* __restrict__ Wp,
           const float* __restrict__ bias,
           const float* __restrict__ his) {
    __shared__ unsigned short tile[4][16 * 136];   // per-wave 16x128 bf16, pad 8
    const int tid = threadIdx.x;
    const int wv = tid >> 6, lane = tid & 63;
    const int m0 = blockIdx.x * 64 + wv * 16;
    if (m0 >= NUM_ENTS) return;
    const int rA = lane & 15, quad = lane >> 4;
    unsigned short* T = tile[wv];

    // stage S tile f32 -> bf16 LDS (wave covers its own 16 rows)
    #pragma unroll
    for (int i = 0; i < 8; ++i) {
        const int idx = i * 64 + lane;
        const int r = idx >> 5, c4 = idx & 31;
        const float4 v = ((const float4*)(io + (size_t)(m0 + r) * HD))[c4];
        ushort4 o;
        o.x = f2bf(v.x); o.y = f2bf(v.y); o.z = f2bf(v.z); o.w = f2bf(v.w);
        *(ushort4*)(T + r * 136 + c4 * 4) = o;
    }

    const bf16x8* WF = (const bf16x8*)Wp;
    f32x4 acc[8];
    #pragma unroll
    for (int t = 0; t < 8; ++t) acc[t] = (f32x4)0.f;

    // phase 1: A = S (LDS), B = Wn ; phase 2: A = h_norm (global hb), B = Ws
    #pragma unroll
    for (int ph = 0; ph < 2; ++ph) {
        bf16x8 a[4];
        if (ph == 0) {
            #pragma unroll
            for (int kt = 0; kt < 4; ++kt)
                a[kt] = *(const bf16x8*)(T + rA * 136 + kt * 32 + quad * 8);
        } else {
            const unsigned short* base = hb + (size_t)(m0 + rA) * HD + quad * 8;
            #pragma unroll
            for (int kt = 0; kt < 4; ++kt)
                a[kt] = *(const bf16x8*)(base + kt * 32);
        }
        #pragma unroll
        for (int t = 0; t < 8; ++t) {
            #pragma unroll
            for (int kt = 0; kt < 4; ++kt) {
                const bf16x8 b = WF[(size_t)(ph * 32 + t * 4 + kt) * 64 + lane];
                acc[t] = __builtin_amdgcn_mfma_f32_16x16x32_bf16(a[kt], b, acc[t], 0, 0, 0);
            }
        }
    }

    // rrelu (C layout: col = t*16 + (lane&15), row = quad*4 + r)
    #pragma unroll
    for (int t = 0; t < 8; ++t)
        #pragma unroll
        for (int r = 0; r < 4; ++r)
            acc[t][r] = acc[t][r] >= 0.f ? acc[t][r] : RRELU_SLOPE * acc[t][r];

    // transpose hcur C-layout -> A-layout via wave-local LDS (bf16)
    #pragma unroll
    for (int t = 0; t < 8; ++t)
        #pragma unroll
        for (int r = 0; r < 4; ++r)
            T[(quad * 4 + r) * 136 + t * 16 + rA] = f2bf(acc[t][r]);

    // phase 3: gate GEMM (B = Wt), bias init
    bf16x8 a3[4];
    #pragma unroll
    for (int kt = 0; kt < 4; ++kt)
        a3[kt] = *(const bf16x8*)(T + rA * 136 + kt * 32 + quad * 8);

    f32x4 acc2[8];
    #pragma unroll
    for (int t = 0; t < 8; ++t) {
        const float bn = bias[t * 16 + rA];
        acc2[t] = (f32x4){bn, bn, bn, bn};
    }
    #pragma unroll
    for (int t = 0; t < 8; ++t) {
        #pragma unroll
        for (int kt = 0; kt < 4; ++kt) {
            const bf16x8 b = WF[(size_t)(64 + t * 4 + kt) * 64 + lane];
            acc2[t] = __builtin_amdgcn_mfma_f32_16x16x32_bf16(a3[kt], b, acc2[t], 0, 0, 0);
        }
    }

    // epilogue: sigmoid gate, blend with his, store (wave's own 16 rows)
    #pragma unroll
    for (int t = 0; t < 8; ++t) {
        const int col = t * 16 + rA;
        #pragma unroll
        for (int r = 0; r < 4; ++r) {
            const size_t row = (size_t)(m0 + quad * 4 + r);
            const float g = 1.f / (1.f + __expf(-acc2[t][r]));
            const float h = his[row * HD + col];
            io[row * HD + col] = g * acc[t][r] + (1.f - g) * h;
        }
    }
}

// ---------- launch ----------
extern "C" void kernel_launch(void* const* d_in, const int* in_sizes, int n_in,
                              void* d_out, int out_size, void* d_ws, size_t ws_size,
                              hipStream_t stream) {
    const float* ent   = (const float*)d_in[0];
    const float* rel   = (const float*)d_in[1];
    const float* his   = (const float*)d_in[2];
    const float* Wn    = (const float*)d_in[3];
    const float* Ws    = (const float*)d_in[4];
    const float* Wt    = (const float*)d_in[5];
    const float* bias  = (const float*)d_in[6];
    const float* enorm = (const float*)d_in[7];
    const int* src = (const int*)d_in[8];
    const int* dst = (const int*)d_in[9];
    const int* ety = (const int*)d_in[10];
    float* out = (float*)d_out;

    // ws: hb 25.6MB | rb 256KB | Wp 96KB | cnt 400KB | offs 400KB | bsum 2KB |
    //     pos 8MB | recs 16MB   (~50.8MB; R2 proved ws >= 51.6MB)
    char* p = (char*)d_ws;
    unsigned short* hb = (unsigned short*)p;  p += (size_t)NUM_ENTS * HD * 2;
    unsigned short* rb = (unsigned short*)p;  p += (size_t)NUM_RELS2 * HD * 2;
    unsigned short* Wp = (unsigned short*)p;  p += (size_t)96 * 64 * 8 * 2;
    int* cnt  = (int*)p;                      p += (size_t)NPAD * 4;
    int* offs = (int*)p;                      p += (size_t)NPAD * 4;
    int* bsum = (int*)p;                      p += 512 * 4;
    int* pos  = (int*)p;                      p += (size_t)NUM_EDGES * 4;
    uint2* recs = (uint2*)p;

    setup_kernel<<<SB_TOTAL, 256, 0, stream>>>(ent, rel, Wn, Ws, Wt, cnt, hb, rb, Wp);
    hist_kernel<<<2048, 256, 0, stream>>>(dst, cnt, pos);
    scan1_kernel<<<NBLK, 256, 0, stream>>>(cnt, offs, bsum);
    scan2_kernel<<<1, 512, 0, stream>>>(bsum);
    scan3_kernel<<<NBLK, 256, 0, stream>>>(offs, bsum);
    permute_kernel<<<2048, 256, 0, stream>>>(dst, src, ety, enorm, offs, pos, recs);
    gather_kernel<<<6250, 256, 0, stream>>>(hb, rb, offs, recs, out /* S in d_out */);
    fused_mfma<<<(NUM_ENTS + 63) / 64, 256, 0, stream>>>(out, hb, Wp, bias, his);
}